// Round 12
// baseline (802.463 us; speedup 1.0000x reference)
//
#include <hip/hip_runtime.h>
#include <hip/hip_fp16.h>

#define Nn 50000
#define Ee 800000
#define Tt 12
#define NBAND 8
#define BAND 6250        // Nn / NBAND exactly
#define CAP 64           // fixed adj slots per node; P(Poisson(16) >= 64) ~ 8e-20
#define NPB 196          // nodes per LDS-staging block: 196*256 = 50176 >= Nn
// adj entry (4 B): (peer << 16) | f16(w).  adjR keyed by r (peer=c), adjC by c.
//
// Session ledger (counter-verified lessons):
//  r1: nt hints -> no change (WRITE_SIZE on atomic kernels = RMW coherency).
//  r2: 1.6M global RMWs == ~68us regardless of pattern. CSR build is done.
//  r3: 16-block LDS-scan scatter -> 210us (0.7% occupancy). Never again.
//  r4: k-outer phase B -> +52us. Keep per-wave wz[36]/wh[36] register form.
//  r5: slotted CSR (start = node<<6, ONE dispatch): 791 -> 730us.
//  r6: branchless gather6: -30us -> not purely latency-chain bound.
//  r7: coop mega-kernel == dispatch loop -> gaps/syncs cheap.
//  r8: 2x occupancy neutral. r9: XCD-affine mapping neutral (699 best).
//  r10: csr 8-way split for instrumentation: +93us (8x edge re-reads). Revert.
//  r11: algebraic cut (static cols precomputed; scalar x gathers): 719.
//      7x fewer gathered BYTES -> only -15% step time => loop cost tracks
//      scattered REQUEST COUNT, not bytes/latency/occupancy/locality.
//  r12 (this): kill scattered global requests entirely. xcur/toX/tiX are
//      100KB each (fits LDS): stage whole source array per block, gathers
//      become ds_read_u16. Loop = gx_lds + t2_lds + dense_step (no gathers).

// ====== csr_direct: banded direct-slot scatter, the whole CSR build ========
__global__ __launch_bounds__(256) void csr_direct(
    const int* __restrict__ ei, const float* __restrict__ ew,
    int* __restrict__ nextR, int* __restrict__ nextC,
    unsigned* __restrict__ adjR, unsigned* __restrict__ adjC)
{
    int band = blockIdx.x & (NBAND - 1);
    int chunk = blockIdx.x >> 3;
    int lo = band * BAND, hi = lo + BAND;
    int stride = (gridDim.x >> 3) * 256;
    for (int e = chunk * 256 + threadIdx.x; e < Ee; e += stride) {
        int r = ei[e], c = ei[Ee + e];
        bool br = (r >= lo) & (r < hi);
        bool bc = (c >= lo) & (c < hi);
        if (br | bc) {
            unsigned wb = __half_as_ushort(__float2half(ew[e]));
            if (br) adjR[(r << 6) + atomicAdd(&nextR[r], 1)] = ((unsigned)c << 16) | wb;
            if (bc) adjC[(c << 6) + atomicAdd(&nextC[c], 1)] = ((unsigned)r << 16) | wb;
        }
    }
}

// ==== effective weights, layout [gate][k*128 + j], k=35 is the bias row ====
// f layout: [0..6]=X, [7..13]=Tx_o, [14..20]=Tx_i, [21..27]=T2_o, [28..34]=T2_i, [35]=1
__global__ __launch_bounds__(256) void weff_kernel(
    const float* __restrict__ Wz, const float* __restrict__ Wh,
    const float* __restrict__ bz, const float* __restrict__ bh,
    float* __restrict__ wzT, float* __restrict__ whT)
{
    int idx = blockIdx.x * 256 + threadIdx.x;
    if (idx >= 2 * 36 * 128) return;
    const float* W = (idx < 36 * 128) ? Wz : Wh;
    const float* B = (idx < 36 * 128) ? bz : bh;
    float* O       = (idx < 36 * 128) ? wzT : whT;
    int rem = idx % (36 * 128);
    int k = rem / 128, j = rem % 128;
    float v;
    if (k == 35) v = B[j];
    else {
        int p = k / 7, rr = k % 7;
        // W flat: ((d*3 + kk)*135 + rr)*128 + j
        if (p == 0)      v = W[(0 * 135 + rr) * 128 + j] + W[(3 * 135 + rr) * 128 + j];
        else if (p == 1) v = W[(1 * 135 + rr) * 128 + j];
        else if (p == 2) v = W[(4 * 135 + rr) * 128 + j];
        else if (p == 3) v = W[(2 * 135 + rr) * 128 + j];
        else             v = W[(5 * 135 + rr) * 128 + j];
    }
    O[k * 128 + j] = v;
}

// == initS: static feature rows S[node][64 f16]: [t*4+c]=env, [48..49]=coords
__global__ __launch_bounds__(256) void initS_kernel(
    const float* __restrict__ x, const float* __restrict__ env,
    const float* __restrict__ coords,
    __half* __restrict__ S, __half* __restrict__ xcur, float* __restrict__ out)
{
    int i = blockIdx.x * 256 + threadIdx.x;
    if (i >= Nn) return;
    float xv = x[i * Tt];
    xcur[i] = __float2half(xv);
    out[i * 13] = xv;
    float4 ev[12];
    const float4* ep = (const float4*)(env + (long)i * 48);
    #pragma unroll
    for (int j = 0; j < 12; j++) ev[j] = ep[j];
    const float* evf = (const float*)ev;
    __half row[64];
    #pragma unroll
    for (int t = 0; t < 12; t++)
        #pragma unroll
        for (int c = 0; c < 4; c++)
            row[t * 4 + c] = __float2half(evf[c * 12 + t]);
    row[48] = __float2half(coords[i * 2]);
    row[49] = __float2half(coords[i * 2 + 1]);
    #pragma unroll
    for (int j = 50; j < 64; j++) row[j] = __half(0.f);
    uint4* dst = (uint4*)(S + (long)i * 64);
    const uint4* sv = (const uint4*)row;
    #pragma unroll
    for (int j = 0; j < 8; j++) dst[j] = sv[j];
}

__device__ __forceinline__ float wdec(unsigned ed) {
    return __half2float(__ushort_as_half((unsigned short)(ed & 0xffffu)));
}

__device__ __forceinline__ void acc8h(float* a, float w, uint4 hv) {
    float2 p0 = __half22float2(*(__half2*)&hv.x);
    float2 p1 = __half22float2(*(__half2*)&hv.y);
    float2 p2 = __half22float2(*(__half2*)&hv.z);
    float2 p3 = __half22float2(*(__half2*)&hv.w);
    a[0] = fmaf(w, p0.x, a[0]); a[1] = fmaf(w, p0.y, a[1]);
    a[2] = fmaf(w, p1.x, a[2]); a[3] = fmaf(w, p1.y, a[3]);
    a[4] = fmaf(w, p2.x, a[4]); a[5] = fmaf(w, p2.y, a[5]);
    a[6] = fmaf(w, p3.x, a[6]); a[7] = fmaf(w, p3.y, a[7]);
}

__device__ __forceinline__ void unpack8h(uint4 hv, float* f) {
    float2 p0 = __half22float2(*(__half2*)&hv.x);
    float2 p1 = __half22float2(*(__half2*)&hv.y);
    float2 p2 = __half22float2(*(__half2*)&hv.z);
    float2 p3 = __half22float2(*(__half2*)&hv.w);
    f[0] = p0.x; f[1] = p0.y; f[2] = p1.x; f[3] = p1.y;
    f[4] = p2.x; f[5] = p2.y; f[6] = p3.x; f[7] = p3.y;
}

// ========== prop: 128B-row propagation over the static columns =============
// Team = 8 lanes per (node,dir); lane s owns 16B chunk s of the 128B row.
// computeInv=1: dst = inv * gather(src); also stores inv (pass 1: src = S).
// computeInv=0: dst = 2*inv*gather(src) - subS   (pass 2: T2 of statics).
__global__ __launch_bounds__(256) void prop_kernel(
    const int* __restrict__ cntR, const unsigned* __restrict__ adjR,
    const int* __restrict__ cntC, const unsigned* __restrict__ adjC,
    const __half* __restrict__ src_o, const __half* __restrict__ src_i,
    const __half* __restrict__ subS,
    __half* __restrict__ dst_o, __half* __restrict__ dst_i,
    float* __restrict__ inv_out, float* __restrict__ inv_in, int computeInv)
{
    int tid = blockIdx.x * 256 + threadIdx.x;
    if (tid >= Nn * 16) return;
    int team = tid >> 3;
    int node = team >> 1, dir = team & 1, s = tid & 7;
    const int*      cn  = dir ? cntC : cntR;
    const unsigned* adj = dir ? adjC : adjR;
    const __half*   src = dir ? src_i : src_o;
    __half*         dst = dir ? dst_i : dst_o;
    int b = node << 6, e = b + cn[node];
    float acc[8] = {0.f,0.f,0.f,0.f,0.f,0.f,0.f,0.f};
    float sw = 0.f;
    for (int k = b; k < e; k += 4) {
        bool v1 = k + 1 < e, v2 = k + 2 < e, v3 = k + 3 < e;
        unsigned e0 = adj[k];
        unsigned e1 = adj[v1 ? k + 1 : b];
        unsigned e2 = adj[v2 ? k + 2 : b];
        unsigned e3 = adj[v3 ? k + 3 : b];
        uint4 r0 = *(const uint4*)(src + (long)(e0 >> 16) * 64 + s * 8);
        uint4 r1 = *(const uint4*)(src + (long)(e1 >> 16) * 64 + s * 8);
        uint4 r2 = *(const uint4*)(src + (long)(e2 >> 16) * 64 + s * 8);
        uint4 r3 = *(const uint4*)(src + (long)(e3 >> 16) * 64 + s * 8);
        float w0 = wdec(e0);
        float w1 = v1 ? wdec(e1) : 0.f;
        float w2 = v2 ? wdec(e2) : 0.f;
        float w3 = v3 ? wdec(e3) : 0.f;
        acc8h(acc, w0, r0); acc8h(acc, w1, r1);
        acc8h(acc, w2, r2); acc8h(acc, w3, r3);
        sw += (w0 + w1) + (w2 + w3);
    }
    float inv;
    if (computeInv) {
        inv = sw > 0.f ? 1.f / sw : 0.f;
        if (s == 0) (dir ? inv_in : inv_out)[node] = inv;
    } else {
        inv = (dir ? inv_in : inv_out)[node];
    }
    float o8[8];
    if (subS) {
        uint4 sv4 = *(const uint4*)(subS + (long)node * 64 + s * 8);
        float sv[8];
        unpack8h(sv4, sv);
        #pragma unroll
        for (int q = 0; q < 8; q++) o8[q] = fmaf(2.f * inv, acc[q], -sv[q]);
    } else {
        #pragma unroll
        for (int q = 0; q < 8; q++) o8[q] = inv * acc[q];
    }
    __half2 h0 = __floats2half2_rn(o8[0], o8[1]);
    __half2 h1 = __floats2half2_rn(o8[2], o8[3]);
    __half2 h2 = __floats2half2_rn(o8[4], o8[5]);
    __half2 h3 = __floats2half2_rn(o8[6], o8[7]);
    uint4 st;
    st.x = *(unsigned*)&h0; st.y = *(unsigned*)&h1;
    st.z = *(unsigned*)&h2; st.w = *(unsigned*)&h3;
    *(uint4*)(dst + (long)node * 64 + s * 8) = st;
}

// ====== gx_lds: Tx of the x column, source STAGED IN LDS (100 KB) ==========
// 256 blocks x 1024 thr, 1 block/CU. Both dirs gather the same staged xcur.
// 8-lane groups per (node,dir); adj reads coalesce (8 consecutive per group).
__global__ __launch_bounds__(1024) void gx_lds(
    const int* __restrict__ cntR, const unsigned* __restrict__ adjR,
    const int* __restrict__ cntC, const unsigned* __restrict__ adjC,
    const __half* __restrict__ xcur,
    __half* __restrict__ toX, __half* __restrict__ tiX,
    const float* __restrict__ inv_out, const float* __restrict__ inv_in)
{
    extern __shared__ __half xs[];   // Nn f16 = 100,000 B
    {
        const uint4* s4 = (const uint4*)xcur;
        uint4* d4 = (uint4*)xs;
        for (int i = threadIdx.x; i < Nn / 8; i += 1024) d4[i] = s4[i];
    }
    __syncthreads();
    int nbase = blockIdx.x * NPB;
    int g = threadIdx.x >> 3, sub = threadIdx.x & 7;   // 128 groups of 8
    for (int p = g; p < 2 * NPB; p += 128) {
        int node = nbase + (p >> 1);
        if (node >= Nn) continue;
        int dir = p & 1;
        const int*      cn  = dir ? cntC : cntR;
        const unsigned* adj = dir ? adjC : adjR;
        int b = node << 6, e = b + cn[node];
        float acc = 0.f;
        for (int k = b + sub; k < e; k += 8) {
            unsigned ed = adj[k];
            acc += wdec(ed) * __half2float(xs[ed >> 16]);
        }
        acc += __shfl_xor(acc, 1);
        acc += __shfl_xor(acc, 2);
        acc += __shfl_xor(acc, 4);
        if (sub == 0) {
            float inv = (dir ? inv_in : inv_out)[node];
            (dir ? tiX : toX)[node] = __float2half(inv * acc);
        }
    }
}

// ====== t2_lds: T2 of the x column; block parity = dir; src staged in LDS ==
__global__ __launch_bounds__(1024) void t2_lds(
    const int* __restrict__ cntR, const unsigned* __restrict__ adjR,
    const int* __restrict__ cntC, const unsigned* __restrict__ adjC,
    const __half* __restrict__ toX, const __half* __restrict__ tiX,
    const __half* __restrict__ xcur,
    const float* __restrict__ inv_out, const float* __restrict__ inv_in,
    float* __restrict__ t2o, float* __restrict__ t2i)
{
    extern __shared__ __half ss[];   // Nn f16
    int dir = blockIdx.x & 1;
    int slice = blockIdx.x >> 1;
    {
        const uint4* s4 = (const uint4*)(dir ? tiX : toX);
        uint4* d4 = (uint4*)ss;
        for (int i = threadIdx.x; i < Nn / 8; i += 1024) d4[i] = s4[i];
    }
    __syncthreads();
    const int*      cn  = dir ? cntC : cntR;
    const unsigned* adj = dir ? adjC : adjR;
    int nbase = slice * NPB;
    int g = threadIdx.x >> 3, sub = threadIdx.x & 7;
    for (int p = g; p < NPB; p += 128) {
        int node = nbase + p;
        if (node >= Nn) continue;
        int b = node << 6, e = b + cn[node];
        float acc = 0.f;
        for (int k = b + sub; k < e; k += 8) {
            unsigned ed = adj[k];
            acc += wdec(ed) * __half2float(ss[ed >> 16]);
        }
        acc += __shfl_xor(acc, 1);
        acc += __shfl_xor(acc, 2);
        acc += __shfl_xor(acc, 4);
        if (sub == 0) {
            float inv = (dir ? inv_in : inv_out)[node];
            (dir ? t2i : t2o)[node] =
                fmaf(2.f * inv, acc, -__half2float(xcur[node]));
        }
    }
}

// ====== dense_step: feature assembly (all sequential reads) + dense ========
__global__ __launch_bounds__(256) void dense_step(
    const float* __restrict__ env, const float* __restrict__ coords,
    const float* __restrict__ night,
    const float* __restrict__ wzT, const float* __restrict__ whT,
    const float* __restrict__ linW, const float* __restrict__ linb,
    __half* __restrict__ xcur,
    const __half* __restrict__ toX, const __half* __restrict__ tiX,
    const float* __restrict__ t2o, const float* __restrict__ t2i,
    const __half* __restrict__ P_o, const __half* __restrict__ P_i,
    const __half* __restrict__ P2_o, const __half* __restrict__ P2_i,
    float* __restrict__ out, int t)
{
    __shared__ float f_s[32][36];
    __shared__ float part_s[2][32];
    int tid = threadIdx.x;
    int base = blockIdx.x * 32;

    // ---- feature fill: 8 disjoint slot-groups, zero scattered reads ----
    {
        int g = tid >> 5;
        int n = tid & 31;
        int node = base + n;
        int nc = node < Nn ? node : Nn - 1;
        if (g == 0) {
            f_s[n][0] = __half2float(xcur[nc]);
            #pragma unroll
            for (int c = 0; c < 4; c++) f_s[n][1 + c] = env[(long)nc * 48 + c * 12 + t];
            f_s[n][5] = coords[nc * 2];
            f_s[n][6] = coords[nc * 2 + 1];
            f_s[n][35] = 1.f;
        } else if (g == 1) {
            f_s[n][7] = __half2float(toX[nc]);
            const __half* r = P_o + (long)nc * 64;
            #pragma unroll
            for (int c = 0; c < 4; c++) f_s[n][8 + c] = __half2float(r[t * 4 + c]);
            f_s[n][12] = __half2float(r[48]);
            f_s[n][13] = __half2float(r[49]);
        } else if (g == 2) {
            f_s[n][14] = __half2float(tiX[nc]);
            const __half* r = P_i + (long)nc * 64;
            #pragma unroll
            for (int c = 0; c < 4; c++) f_s[n][15 + c] = __half2float(r[t * 4 + c]);
            f_s[n][19] = __half2float(r[48]);
            f_s[n][20] = __half2float(r[49]);
        } else if (g == 3) {
            f_s[n][21] = t2o[nc];
            const __half* r = P2_o + (long)nc * 64;
            #pragma unroll
            for (int c = 0; c < 4; c++) f_s[n][22 + c] = __half2float(r[t * 4 + c]);
            f_s[n][26] = __half2float(r[48]);
            f_s[n][27] = __half2float(r[49]);
        } else if (g == 4) {
            f_s[n][28] = t2i[nc];
            const __half* r = P2_i + (long)nc * 64;
            #pragma unroll
            for (int c = 0; c < 4; c++) f_s[n][29 + c] = __half2float(r[t * 4 + c]);
            f_s[n][33] = __half2float(r[48]);
            f_s[n][34] = __half2float(r[49]);
        }
    }
    __syncthreads();

    // ---- phase B: dense 36x128x2 contraction + activations + output ----
    int lane = tid & 63;
    int wave = tid >> 6;
    int chSel = wave & 1;
    int ch = chSel * 64 + lane;
    int half_id = wave >> 1;
    float wz[36], wh[36];
    #pragma unroll
    for (int k = 0; k < 36; k++) wz[k] = wzT[k * 128 + ch];
    #pragma unroll
    for (int k = 0; k < 36; k++) wh[k] = whT[k * 128 + ch];
    float lw = linW[ch];
    float lb = linb[0];

    #pragma unroll 1
    for (int n = 0; n < 16; n++) {
        int ni = half_id * 16 + n;
        const float4* fv = (const float4*)f_s[ni];   // broadcast reads
        float hz = 0.f, hh = 0.f;
        #pragma unroll
        for (int q = 0; q < 9; q++) {
            float4 fq = fv[q];
            hz = fmaf(fq.x, wz[q*4+0], hz); hh = fmaf(fq.x, wh[q*4+0], hh);
            hz = fmaf(fq.y, wz[q*4+1], hz); hh = fmaf(fq.y, wh[q*4+1], hh);
            hz = fmaf(fq.z, wz[q*4+2], hz); hh = fmaf(fq.z, wh[q*4+2], hh);
            hz = fmaf(fq.w, wz[q*4+3], hz); hh = fmaf(fq.w, wh[q*4+3], hh);
        }
        float z  = 1.f / (1.f + __expf(-hz));
        float e2 = __expf(2.f * hh);
        float ht = 1.f - 2.f / (e2 + 1.f);           // tanh
        float v = fmaxf((1.f - z) * ht, 0.f) * lw;   // (1-Z)*H~, relu, lin
        v += __shfl_xor(v, 1);  v += __shfl_xor(v, 2);  v += __shfl_xor(v, 4);
        v += __shfl_xor(v, 8);  v += __shfl_xor(v, 16); v += __shfl_xor(v, 32);
        if (lane == 0) part_s[chSel][ni] = v;
    }
    __syncthreads();
    if (tid < 32) {
        int node = base + tid;
        if (node < Nn) {
            float o = part_s[0][tid] + part_s[1][tid] + lb;
            o *= night[(long)node * 13 + t + 1];
            out[(long)node * 13 + t + 1] = o;
            if (t + 1 < Tt) xcur[node] = __float2half(o);
        }
    }
}

extern "C" void kernel_launch(void* const* d_in, const int* in_sizes, int n_in,
                              void* d_out, int out_size, void* d_ws, size_t ws_size,
                              hipStream_t stream) {
    const float* x      = (const float*)d_in[0];
    const float* env    = (const float*)d_in[1];
    const float* coords = (const float*)d_in[2];
    const int*   ei     = (const int*)d_in[3];
    const float* ew     = (const float*)d_in[4];
    const float* night  = (const float*)d_in[5];
    const float* Wz     = (const float*)d_in[6];
    const float* bz     = (const float*)d_in[7];
    // d_in[8]=Wr, d_in[9]=br unused (R gate never affects output)
    const float* Wh     = (const float*)d_in[10];
    const float* bh     = (const float*)d_in[11];
    const float* linW   = (const float*)d_in[12];
    const float* linb   = (const float*)d_in[13];
    float* out = (float*)d_out;

    float* w = (float*)d_ws;                // ws_size ~268MB
    float* wzT     = w;                     // 36*128
    float* whT     = w + 4608;
    float* inv_out = w + 9216;              // N f32
    float* inv_in  = w + 59216;
    __half* xcur   = (__half*)(w + 109216); // N f16 (100,000 B)
    __half* toX    = (__half*)(w + 134216); // N f16
    __half* tiX    = (__half*)(w + 159216); // N f16
    float* t2o     = w + 184216;            // N f32
    float* t2i     = w + 234216;            // N f32
    int* nextR     = (int*)(w + 284216);    // N; doubles as cntR
    int* nextC     = (int*)(w + 334216);    // N; doubles as cntC
    __half* S    = (__half*)(w + 384224);   // N x 64 f16 rows (128 B, aligned)
    __half* P_o  = (__half*)(w + 1984224);
    __half* P_i  = (__half*)(w + 3584224);
    __half* P2_o = (__half*)(w + 5184224);
    __half* P2_i = (__half*)(w + 6784224);
    unsigned* adjR = (unsigned*)(w + 8384224);   // N*64 x 4B
    unsigned* adjC = (unsigned*)(w + 11584224);  // end ~59.1 MB

    static bool attrSet = false;
    if (!attrSet) {
        hipFuncSetAttribute((const void*)gx_lds,
            hipFuncAttributeMaxDynamicSharedMemorySize, Nn * 2);
        hipFuncSetAttribute((const void*)t2_lds,
            hipFuncAttributeMaxDynamicSharedMemorySize, Nn * 2);
        attrSet = true;   // ignore errors; launch works without it on AMD
    }

    // ---- CSR build: single direct-slot scatter (r5 proven form) ----
    hipMemsetAsync(nextR, 0, 2 * Nn * sizeof(int), stream);
    csr_direct<<<8 * 256, 256, 0, stream>>>(ei, ew, nextR, nextC, adjR, adjC);

    weff_kernel<<<36, 256, 0, stream>>>(Wz, Wh, bz, bh, wzT, whT);
    initS_kernel<<<(Nn + 255) / 256, 256, 0, stream>>>(x, env, coords, S, xcur, out);

    // ---- precompute: prop and second-order of all static columns ----
    prop_kernel<<<(Nn * 16) / 256, 256, 0, stream>>>(
        nextR, adjR, nextC, adjC, S, S, nullptr, P_o, P_i, inv_out, inv_in, 1);
    prop_kernel<<<(Nn * 16) / 256, 256, 0, stream>>>(
        nextR, adjR, nextC, adjC, P_o, P_i, S, P2_o, P2_i, inv_out, inv_in, 0);

    // ---- time loop: LDS-staged scalar props + gather-free dense ----
    for (int t = 0; t < Tt; t++) {
        gx_lds<<<256, 1024, Nn * 2, stream>>>(
            nextR, adjR, nextC, adjC, xcur, toX, tiX, inv_out, inv_in);
        t2_lds<<<512, 1024, Nn * 2, stream>>>(
            nextR, adjR, nextC, adjC, toX, tiX, xcur, inv_out, inv_in, t2o, t2i);
        dense_step<<<(Nn + 31) / 32, 256, 0, stream>>>(
            env, coords, night, wzT, whT, linW, linb,
            xcur, toX, tiX, t2o, t2i, P_o, P_i, P2_o, P2_i, out, t);
    }
}

// Round 13
// 700.337 us; speedup vs baseline: 1.1458x; 1.1458x over previous
//
#include <hip/hip_runtime.h>
#include <hip/hip_fp16.h>

#define Nn 50000
#define Ee 800000
#define Tt 12
#define NBAND 8
#define BAND 6250        // Nn / NBAND exactly
#define CAP 64           // fixed adj slots per node; P(Poisson(16) >= 64) ~ 8e-20
#define NCHUNK ((Nn * 8 + 255) / 256)   // 1563 gather chunks (256 thr each)
#define NWI ((Nn + 31) / 32)            // 1563 step2 work items
#define BPB 196                          // blocks per band: 8*196 = 1568 >= 1563
// HID=128, K=3, F_IN=7, effective features = 35 (+1 bias slot)
// Node feature rows: 8 x f16 = 16 B (one dwordx4 gather).
// adj entry (4 B): (peer << 16) | f16(w).  adjR keyed by r (peer=c), adjC by c.
//
// Session ledger (counter-verified lessons) — FINAL:
//  r1: nt hints -> no change (WRITE_SIZE on atomic kernels = RMW coherency).
//  r2: 1.6M global RMWs == ~68us regardless of pattern (~23G RMW/s fabric).
//  r3: 16-block LDS-scan scatter -> 210us (0.7% occupancy). Never again.
//  r4: k-outer phase B -> +52us. Keep per-wave wz[36]/wh[36] register form.
//  r5: slotted CSR (start = node<<6, ONE dispatch): 791 -> 730us.
//  r6: branchless gather6: -30us (one latency exposure for deg<=24).
//  r7: coop mega-kernel == dispatch loop -> boundaries and grid syncs cost
//      the same (~9-10us each); 2 device-wide barriers/step are structural
//      (two-hop recurrence: Tx_t must be globally complete before T2_t).
//  r8: 2x occupancy neutral. r9: XCD-affine mapping neutral. 699us best.
//  r10: dispatch splitting costs ~9-10us each (csr 8-way: +93us). Revert.
//  r11: 7x fewer gathered bytes -> only -15% step time: loop cost tracks
//      scattered REQUEST count (3.2M/step @ ~62G req/s), not bytes.
//  r12: LDS-staged sources: 77MB/step stage amplification + 12 extra
//      boundaries -> 802us. Revert.
//  r13 (this): restore the r9 champion. 3.2M scattered requests/step is
//      algorithmically irreducible (deg^2 recompute or in-loop RMWs are
//      strictly worse by measured rates); all macro levers measured neutral.
//      This is the practical floor of this work shape on this machine.

// ====== csr_direct: banded direct-slot scatter, the whole CSR build ========
__global__ __launch_bounds__(256) void csr_direct(
    const int* __restrict__ ei, const float* __restrict__ ew,
    int* __restrict__ nextR, int* __restrict__ nextC,
    unsigned* __restrict__ adjR, unsigned* __restrict__ adjC)
{
    int band = blockIdx.x & (NBAND - 1);
    int chunk = blockIdx.x >> 3;
    int lo = band * BAND, hi = lo + BAND;
    int stride = (gridDim.x >> 3) * 256;
    for (int e = chunk * 256 + threadIdx.x; e < Ee; e += stride) {
        int r = ei[e], c = ei[Ee + e];
        bool br = (r >= lo) & (r < hi);
        bool bc = (c >= lo) & (c < hi);
        if (br | bc) {
            unsigned wb = __half_as_ushort(__float2half(ew[e]));
            if (br) adjR[(r << 6) + atomicAdd(&nextR[r], 1)] = ((unsigned)c << 16) | wb;
            if (bc) adjC[(c << 6) + atomicAdd(&nextC[c], 1)] = ((unsigned)r << 16) | wb;
        }
    }
}

// ==== effective weights, layout [gate][k*128 + j], k=35 is the bias row ====
// f layout: [0..6]=X, [7..13]=Tx_o, [14..20]=Tx_i, [21..27]=T2_o, [28..34]=T2_i, [35]=1
__global__ __launch_bounds__(256) void weff_kernel(
    const float* __restrict__ Wz, const float* __restrict__ Wh,
    const float* __restrict__ bz, const float* __restrict__ bh,
    float* __restrict__ wzT, float* __restrict__ whT)
{
    int idx = blockIdx.x * 256 + threadIdx.x;
    if (idx >= 2 * 36 * 128) return;
    const float* W = (idx < 36 * 128) ? Wz : Wh;
    const float* B = (idx < 36 * 128) ? bz : bh;
    float* O       = (idx < 36 * 128) ? wzT : whT;
    int rem = idx % (36 * 128);
    int k = rem / 128, j = rem % 128;
    float v;
    if (k == 35) v = B[j];
    else {
        int p = k / 7, rr = k % 7;
        // W flat: ((d*3 + kk)*135 + rr)*128 + j
        if (p == 0)      v = W[(0 * 135 + rr) * 128 + j] + W[(3 * 135 + rr) * 128 + j];
        else if (p == 1) v = W[(1 * 135 + rr) * 128 + j];
        else if (p == 2) v = W[(4 * 135 + rr) * 128 + j];
        else if (p == 3) v = W[(2 * 135 + rr) * 128 + j];
        else             v = W[(5 * 135 + rr) * 128 + j];
    }
    O[k * 128 + j] = v;
}

// =================== init: Xh row (f16) and out column 0 ===================
__global__ __launch_bounds__(256) void init_kernel(
    const float* __restrict__ x, const float* __restrict__ env,
    const float* __restrict__ coords, __half* __restrict__ Xh,
    float* __restrict__ out)
{
    int i = blockIdx.x * 256 + threadIdx.x;
    if (i >= Nn) return;
    float xv = x[i * Tt];
    __half* r = Xh + (long)i * 8;
    r[0] = __float2half(xv);
    #pragma unroll
    for (int c = 0; c < 4; c++) r[1 + c] = __float2half(env[i * 48 + c * 12]);
    r[5] = __float2half(coords[i * 2 + 0]);
    r[6] = __float2half(coords[i * 2 + 1]);
    r[7] = __half(0.f);
    out[i * 13 + 0] = xv;
}

__device__ __forceinline__ void unpack8(const __half* p, float* v) {
    uint4 hv = *((const uint4*)p);
    float2 p0 = __half22float2(*(__half2*)&hv.x);
    float2 p1 = __half22float2(*(__half2*)&hv.y);
    float2 p2 = __half22float2(*(__half2*)&hv.z);
    float2 p3 = __half22float2(*(__half2*)&hv.w);
    v[0] = p0.x; v[1] = p0.y; v[2] = p1.x; v[3] = p1.y;
    v[4] = p2.x; v[5] = p2.y; v[6] = p3.x;
}

__device__ __forceinline__ void pack8(__half* p, const float* v) {
    __half2 q0 = __floats2half2_rn(v[0], v[1]);
    __half2 q1 = __floats2half2_rn(v[2], v[3]);
    __half2 q2 = __floats2half2_rn(v[4], v[5]);
    __half2 q3 = __floats2half2_rn(v[6], 0.f);
    uint4 st;
    st.x = *(unsigned*)&q0; st.y = *(unsigned*)&q1;
    st.z = *(unsigned*)&q2; st.w = *(unsigned*)&q3;
    *((uint4*)p) = st;
}

// accumulate a[0..6] += w * halfrow(hv)
__device__ __forceinline__ void acc7(float* a, float w, uint4 hv) {
    float2 p0 = __half22float2(*(__half2*)&hv.x);
    float2 p1 = __half22float2(*(__half2*)&hv.y);
    float2 p2 = __half22float2(*(__half2*)&hv.z);
    float2 p3 = __half22float2(*(__half2*)&hv.w);
    a[0] = fmaf(w, p0.x, a[0]); a[1] = fmaf(w, p0.y, a[1]);
    a[2] = fmaf(w, p1.x, a[2]); a[3] = fmaf(w, p1.y, a[3]);
    a[4] = fmaf(w, p2.x, a[4]); a[5] = fmaf(w, p2.y, a[5]);
    a[6] = fmaf(w, p3.x, a[6]);
}

__device__ __forceinline__ float wdec(unsigned ed) {
    return __half2float(__ushort_as_half((unsigned short)(ed & 0xffffu)));
}

// Branchless fixed-depth gather core (r6): 6 slots stride 4 covers deg<=24
// in one latency exposure; rare fallback loop beyond.
__device__ __forceinline__ void gather6(
    const unsigned* __restrict__ adj, const __half* __restrict__ src,
    int b, int k0, int e, float* a, float* sw)
{
    unsigned en[6];
    bool v[6];
    #pragma unroll
    for (int s = 0; s < 6; s++) {
        int k = k0 + 4 * s;
        v[s] = k < e;
        en[s] = adj[v[s] ? k : b];
    }
    uint4 rv[6];
    #pragma unroll
    for (int s = 0; s < 6; s++)
        rv[s] = *(const uint4*)(src + (long)(v[s] ? (en[s] >> 16) : 0u) * 8);
    #pragma unroll
    for (int s = 0; s < 6; s++) {
        float w = v[s] ? wdec(en[s]) : 0.f;
        acc7(a, w, rv[s]);
        if (sw) *sw += w;
    }
    for (int k = k0 + 24; k < e; k += 4) {    // rare: deg > 24
        unsigned ed = adj[k];
        uint4 r2 = *(const uint4*)(src + (long)(ed >> 16) * 8);
        float w = wdec(ed);
        acc7(a, w, r2);
        if (sw) *sw += w;
    }
}

// ============== gather pass 1: Tx = inv * segsum(w * Xh[src]) ==============
// Band-affine: blockIdx%8 = band = XCD; chunk = band*BPB + blockIdx/8.
__global__ __launch_bounds__(256) void gather1_kernel(
    const int* __restrict__ cntR, const unsigned* __restrict__ adjR,
    const int* __restrict__ cntC, const unsigned* __restrict__ adjC,
    const __half* __restrict__ Xh,
    __half* __restrict__ TxoH, __half* __restrict__ TxiH,
    float* __restrict__ inv_out, float* __restrict__ inv_in)
{
    int beta = blockIdx.x & (NBAND - 1);
    int j = blockIdx.x >> 3;
    int chunk = beta * BPB + j;
    if (chunk >= NCHUNK) return;
    int tid = chunk * 256 + threadIdx.x;
    if (tid >= Nn * 8) return;
    int node = tid >> 3;
    int dir = (tid >> 2) & 1, sub = tid & 3;
    const int*      cn  = dir ? cntC : cntR;
    const unsigned* adj = dir ? adjC : adjR;
    int b = node << 6, e = b + cn[node];
    float a[7] = {0.f, 0.f, 0.f, 0.f, 0.f, 0.f, 0.f};
    float sw = 0.f;
    gather6(adj, Xh, b, b + sub, e, a, &sw);
    #pragma unroll
    for (int m = 1; m <= 2; m <<= 1) {
        #pragma unroll
        for (int q = 0; q < 7; q++) a[q] += __shfl_xor(a[q], m);
        sw += __shfl_xor(sw, m);
    }
    if (sub == 0) {
        float inv = sw > 0.f ? 1.f / sw : 0.f;
        (dir ? inv_in : inv_out)[node] = inv;
        #pragma unroll
        for (int q = 0; q < 7; q++) a[q] *= inv;
        pack8((dir ? TxiH : TxoH) + (long)node * 8, a);
    }
}

// ====== fused step2: second-order propagation (into LDS, fp32) + dense =====
// Band-affine: wi = (blockIdx%8)*BPB + blockIdx/8.
__global__ __launch_bounds__(256) void step2_kernel(
    const int* __restrict__ cntR, const unsigned* __restrict__ adjR,
    const int* __restrict__ cntC, const unsigned* __restrict__ adjC,
    const float* __restrict__ inv_out, const float* __restrict__ inv_in,
    const float* __restrict__ env, const float* __restrict__ night,
    const float* __restrict__ wzT, const float* __restrict__ whT,
    const float* __restrict__ linW, const float* __restrict__ linb,
    __half* __restrict__ Xh,
    const __half* __restrict__ TxoH, const __half* __restrict__ TxiH,
    float* __restrict__ out, int t)
{
    int beta = blockIdx.x & (NBAND - 1);
    int j = blockIdx.x >> 3;
    int wi = beta * BPB + j;
    if (wi >= NWI) return;

    __shared__ float f_s[32][36];
    __shared__ float part_s[2][32];
    int tid = threadIdx.x;
    int base = wi * 32;

    // ---- phase A: T2 for this item's 32 nodes, straight into LDS ----
    {
        int nl = tid >> 3;
        int dir = (tid >> 2) & 1, sub = tid & 3;
        int node = base + nl;
        int nc = node < Nn ? node : Nn - 1;   // clamp; output stores guarded
        const int*      cn  = dir ? cntC : cntR;
        const unsigned* adj = dir ? adjC : adjR;
        const __half*   src = dir ? TxiH : TxoH;
        int b = nc << 6, e = b + cn[nc];
        float a[7] = {0.f, 0.f, 0.f, 0.f, 0.f, 0.f, 0.f};
        gather6(adj, src, b, b + sub, e, a, nullptr);
        #pragma unroll
        for (int m = 1; m <= 2; m <<= 1) {
            #pragma unroll
            for (int q = 0; q < 7; q++) a[q] += __shfl_xor(a[q], m);
        }
        if (sub == 0) {
            float s2 = 2.f * (dir ? inv_in[nc] : inv_out[nc]);
            float xv[7], tx[7];
            unpack8(Xh + (long)nc * 8, xv);
            unpack8(src + (long)nc * 8, tx);     // own Tx row (dir-matched)
            #pragma unroll
            for (int q = 0; q < 7; q++) {
                f_s[nl][21 + 7 * dir + q] = fmaf(s2, a[q], -xv[q]);
                f_s[nl][7 + 7 * dir + q]  = tx[q];
            }
            if (dir == 0) {
                #pragma unroll
                for (int q = 0; q < 7; q++) f_s[nl][q] = xv[q];
                f_s[nl][35] = 1.f;
            }
        }
    }
    __syncthreads();

    // ---- phase B: dense 36x128x2 contraction + activations + output ----
    int lane = tid & 63;
    int wave = tid >> 6;
    int chSel = wave & 1;
    int ch = chSel * 64 + lane;
    int half_id = wave >> 1;
    float wz[36], wh[36];
    #pragma unroll
    for (int k = 0; k < 36; k++) wz[k] = wzT[k * 128 + ch];
    #pragma unroll
    for (int k = 0; k < 36; k++) wh[k] = whT[k * 128 + ch];
    float lw = linW[ch];
    float lb = linb[0];

    #pragma unroll 1
    for (int n = 0; n < 16; n++) {
        int ni = half_id * 16 + n;
        const float4* fv = (const float4*)f_s[ni];   // broadcast reads
        float hz = 0.f, hh = 0.f;
        #pragma unroll
        for (int q = 0; q < 9; q++) {
            float4 fq = fv[q];
            hz = fmaf(fq.x, wz[q*4+0], hz); hh = fmaf(fq.x, wh[q*4+0], hh);
            hz = fmaf(fq.y, wz[q*4+1], hz); hh = fmaf(fq.y, wh[q*4+1], hh);
            hz = fmaf(fq.z, wz[q*4+2], hz); hh = fmaf(fq.z, wh[q*4+2], hh);
            hz = fmaf(fq.w, wz[q*4+3], hz); hh = fmaf(fq.w, wh[q*4+3], hh);
        }
        float z  = 1.f / (1.f + __expf(-hz));
        float e2 = __expf(2.f * hh);
        float ht = 1.f - 2.f / (e2 + 1.f);           // tanh
        float v = fmaxf((1.f - z) * ht, 0.f) * lw;   // (1-Z)*H~, relu, lin
        v += __shfl_xor(v, 1);  v += __shfl_xor(v, 2);  v += __shfl_xor(v, 4);
        v += __shfl_xor(v, 8);  v += __shfl_xor(v, 16); v += __shfl_xor(v, 32);
        if (lane == 0) part_s[chSel][ni] = v;
    }
    __syncthreads();
    if (tid < 32) {
        int node = base + tid;
        if (node < Nn) {
            float o = part_s[0][tid] + part_s[1][tid] + lb;
            o *= night[(long)node * 13 + t + 1];
            out[(long)node * 13 + t + 1] = o;
            if (t + 1 < Tt) {
                __half* xr = Xh + (long)node * 8;
                xr[0] = __float2half(o);
                #pragma unroll
                for (int c = 0; c < 4; c++)
                    xr[1 + c] = __float2half(env[(long)node * 48 + c * 12 + t + 1]);
            }
        }
    }
}

extern "C" void kernel_launch(void* const* d_in, const int* in_sizes, int n_in,
                              void* d_out, int out_size, void* d_ws, size_t ws_size,
                              hipStream_t stream) {
    const float* x      = (const float*)d_in[0];
    const float* env    = (const float*)d_in[1];
    const float* coords = (const float*)d_in[2];
    const int*   ei     = (const int*)d_in[3];
    const float* ew     = (const float*)d_in[4];
    const float* night  = (const float*)d_in[5];
    const float* Wz     = (const float*)d_in[6];
    const float* bz     = (const float*)d_in[7];
    // d_in[8]=Wr, d_in[9]=br unused (R gate never affects output)
    const float* Wh     = (const float*)d_in[10];
    const float* bh     = (const float*)d_in[11];
    const float* linW   = (const float*)d_in[12];
    const float* linb   = (const float*)d_in[13];
    float* out = (float*)d_out;

    float* w = (float*)d_ws;
    float* wzT     = w;                     // 36*128
    float* whT     = w + 4608;
    float* inv_out = w + 9216;              // N
    float* inv_in  = w + 59216;
    __half* Xh   = (__half*)(w + 109216);   // N x 8 halves (16B-aligned offsets)
    __half* TxoH = (__half*)(w + 309216);
    __half* TxiH = (__half*)(w + 509216);
    int* nextR   = (int*)(w + 709216);      // N; doubles as cntR after scatter
    int* nextC   = nextR + 50000;           // N; doubles as cntC
    unsigned* adjR = (unsigned*)(w + 809280);    // N*64 slots x 4B = 12.8 MB
    unsigned* adjC = adjR + Nn * CAP;            // 12.8 MB; end ~ 28.8 MB

    // ---- CSR build: single direct-slot scatter (1.6M RMWs total) ----
    hipMemsetAsync(nextR, 0, 2 * Nn * sizeof(int), stream);
    csr_direct<<<8 * 256, 256, 0, stream>>>(ei, ew, nextR, nextC, adjR, adjC);

    weff_kernel<<<36, 256, 0, stream>>>(Wz, Wh, bz, bh, wzT, whT);
    init_kernel<<<(Nn + 255) / 256, 256, 0, stream>>>(x, env, coords, Xh, out);

    // ---- time loop: 24 dispatches, band-affine block mapping ----
    for (int t = 0; t < Tt; t++) {
        gather1_kernel<<<8 * BPB, 256, 0, stream>>>(
            nextR, adjR, nextC, adjC, Xh, TxoH, TxiH, inv_out, inv_in);
        step2_kernel<<<8 * BPB, 256, 0, stream>>>(
            nextR, adjR, nextC, adjC, inv_out, inv_in,
            env, night, wzT, whT, linW, linb, Xh, TxoH, TxiH, out, t);
    }
}